// Round 16
// baseline (182.484 us; speedup 1.0000x reference)
//
#include <hip/hip_runtime.h>
#include <hip/hip_bf16.h>

#define NH 12
#define HD 64
#define NB 4
#define SEQ 2048
#define NP 768
#define LOG2E 1.44269504f
#define MASK_L2 14426.9504f   // 10000 * log2(e)

typedef __bf16 bf16x8 __attribute__((ext_vector_type(8)));
typedef __bf16 bf16x2 __attribute__((ext_vector_type(2)));
typedef float f32x2 __attribute__((ext_vector_type(2)));
typedef float f32x4 __attribute__((ext_vector_type(4)));
typedef float f32x16 __attribute__((ext_vector_type(16)));
typedef unsigned u32x4 __attribute__((ext_vector_type(4)));

static __device__ __forceinline__ bf16x8 load_bf16x8(const __bf16* p) {
    return *reinterpret_cast<const bf16x8*>(p);
}
static __device__ __forceinline__ float hw_exp2(float x) {
    return __builtin_amdgcn_exp2f(x);
}
static __device__ __forceinline__ unsigned cvtpk2(float lo, float hi) {
    f32x2 t; t[0] = lo; t[1] = hi;
    return __builtin_bit_cast(unsigned, __builtin_convertvector(t, bf16x2));
}

// ---------------------------------------------------------------------------
// Kernel 1 (round-13 restore, best-measured gap): QKV projection with
// in-block W transpose staging. grid (128, 2): 18 (proj,head) tiles/block.
// Vf in SIGMA-PERMUTED key order sigma(8*hi+j) = (j&3)+8*(j>>2)+4*hi.
// ---------------------------------------------------------------------------
__global__ __launch_bounds__(256) void qkv_kernel(
    const float* __restrict__ hidden,
    const float* __restrict__ Wq, const float* __restrict__ Wk,
    const float* __restrict__ Wv,
    const float* __restrict__ bq, const float* __restrict__ bk,
    const float* __restrict__ bv,
    __bf16* __restrict__ Qw, __bf16* __restrict__ Kf, __bf16* __restrict__ Vf)
{
    __shared__ __bf16 wtileT[64][72];   // [c][k]
    __shared__ __bf16 ot[64][72];       // [t][c]

    const int tid  = threadIdx.x;
    const int lane = tid & 63;
    const int w    = tid >> 6;
    const int g    = lane >> 4;
    const int n    = lane & 15;
    const int n32  = lane & 31;
    const int hi   = lane >> 5;

    const int row0 = blockIdx.x * 64;
    const int gi   = blockIdx.y;          // 0..1
    const int b_   = row0 >> 11;
    const int t0   = row0 & (SEQ - 1);
    const int kb64 = t0 >> 6;

    const float* hrow = hidden + (size_t)(row0 + w * 16 + n) * HD + 8 * g;
    f32x4 h0 = *(const f32x4*)(hrow);
    f32x4 h1 = *(const f32x4*)(hrow + 4);
    f32x4 h2 = *(const f32x4*)(hrow + 32);
    f32x4 h3 = *(const f32x4*)(hrow + 36);
    bf16x8 a0, a1;
    #pragma unroll
    for (int j = 0; j < 4; ++j) {
        a0[j]     = (__bf16)h0[j];
        a0[j + 4] = (__bf16)h1[j];
        a1[j]     = (__bf16)h2[j];
        a1[j + 4] = (__bf16)h3[j];
    }

    const int dr   = tid >> 2;        // 0..63 (W row = k)
    const int coff = (tid & 3) * 16;  // 16 consecutive cols

    for (int tt = 0; tt < 18; ++tt) {
        const int tile_id = gi * 18 + tt;      // 0..35
        const int proj    = tile_id / 12;
        const int head    = tile_id % 12;
        const int bh      = b_ * NH + head;
        const float* W    = proj == 0 ? Wq : (proj == 1 ? Wk : Wv);
        const float* bias = proj == 0 ? bq : (proj == 1 ? bk : bv);
        const float qs    = (proj == 0) ? 0.125f * LOG2E : 1.0f;

        const float* wr = W + (size_t)dr * NP + head * 64 + coff;
        f32x4 x0 = *(const f32x4*)(wr);
        f32x4 x1 = *(const f32x4*)(wr + 4);
        f32x4 x2 = *(const f32x4*)(wr + 8);
        f32x4 x3 = *(const f32x4*)(wr + 12);
        #pragma unroll
        for (int i = 0; i < 4; ++i) {
            wtileT[coff + i     ][dr] = (__bf16)(x0[i] * qs);
            wtileT[coff + 4 + i ][dr] = (__bf16)(x1[i] * qs);
            wtileT[coff + 8 + i ][dr] = (__bf16)(x2[i] * qs);
            wtileT[coff + 12 + i][dr] = (__bf16)(x3[i] * qs);
        }
        __syncthreads();   // wtileT ready; also fences prev tile's ot reads

        #pragma unroll
        for (int dt = 0; dt < 4; ++dt) {
            const bf16x8 b0 = *(const bf16x8*)&wtileT[dt * 16 + n][8 * g];
            const bf16x8 b1 = *(const bf16x8*)&wtileT[dt * 16 + n][32 + 8 * g];
            f32x4 acc = {0.f, 0.f, 0.f, 0.f};
            acc = __builtin_amdgcn_mfma_f32_16x16x32_bf16(a0, b0, acc, 0, 0, 0);
            acc = __builtin_amdgcn_mfma_f32_16x16x32_bf16(a1, b1, acc, 0, 0, 0);
            const float bb = bias[head * 64 + dt * 16 + n] * qs;
            #pragma unroll
            for (int r = 0; r < 4; ++r)
                ot[w * 16 + 4 * g + r][dt * 16 + n] = (__bf16)(acc[r] + bb);
        }
        __syncthreads();   // ot complete; wtileT frag reads done

        if (proj == 0) {
            __bf16* dst = Qw + ((size_t)bh * SEQ + t0 + w * 16) * HD;
            const int tr = lane >> 2;
            const int d0 = (lane & 3) * 16;
            *(bf16x8*)(dst + (size_t)tr * HD + d0)     = *(const bf16x8*)&ot[w * 16 + tr][d0];
            *(bf16x8*)(dst + (size_t)tr * HD + d0 + 8) = *(const bf16x8*)&ot[w * 16 + tr][d0 + 8];
        } else if (proj == 1) {
            __bf16* base = Kf + (size_t)bh * SEQ * HD + (size_t)kb64 * 4096;
            #pragma unroll
            for (int sub = 0; sub < 2; ++sub) {
                const bf16x8 fr = *(const bf16x8*)&ot[sub * 32 + n32][w * 16 + 8 * hi];
                *(bf16x8*)(base + (size_t)(w * 2 + sub) * 512 + lane * 8) = fr;
            }
        } else {
            __bf16* base = Vf + (size_t)bh * SEQ * HD + (size_t)kb64 * 4096;
            #pragma unroll
            for (int dsub = 0; dsub < 2; ++dsub) {
                bf16x8 v;
                #pragma unroll
                for (int j = 0; j < 8; ++j)
                    v[j] = ot[w * 16 + ((j & 3) + 8 * (j >> 2) + 4 * hi)][dsub * 32 + n32];
                *(bf16x8*)(base + (size_t)(w * 2 + dsub) * 512 + lane * 8) = v;
            }
        }
    }
}

// ---------------------------------------------------------------------------
// Kernel 2 v16: key-split flash, SOFTWARE-PIPELINED at 32-key half-iter
// granularity: S for half h+1 (K prefetched 2 halves ahead) is issued BEFORE
// exp/pack of half h, so the 5 S-MFMAs execute in the matrix pipe while the
// VALU does the exp burst — removing the intra-wave matrix-idle phase that
// survived v11-v13. 16 half-iters of 32 keys per wave.
// ---------------------------------------------------------------------------
__global__ __launch_bounds__(256, 3) void flash_attn_kernel(
    const __bf16* __restrict__ Qw, const __bf16* __restrict__ Kf,
    const __bf16* __restrict__ Vf, const float* __restrict__ amask,
    float* __restrict__ out)
{
    __shared__ __align__(16) char smem[35328];
    __bf16* mdd = (__bf16*)smem;                      // loop phase (4 KB)
    float (*et)[32][68] = (float(*)[32][68])smem;     // epilogue (34,816 B)
    float* lrow = (float*)(smem + 34816);             // epilogue (512 B)

    const int tid  = threadIdx.x;
    const int lane = tid & 63;
    const int w    = tid >> 6;
    const int n32  = lane & 31;
    const int hi   = lane >> 5;

    const int bid    = blockIdx.x;        // 3072
    const int xcd    = bid & 7;
    const int slot   = bid >> 3;          // 0..383
    const int bh     = xcd * 6 + (slot >> 6);
    const int qchunk = slot & 63;
    const int b_     = bh / NH;
    const int h      = bh % NH;
    const int q0     = qchunk * 32;

    const float* mp = amask + (size_t)b_ * SEQ;
    #pragma unroll
    for (int i = 0; i < 8; ++i) {
        const int idx = w * 512 + i * 64 + lane;
        mdd[idx] = (__bf16)fmaf(mp[idx], MASK_L2, -MASK_L2);
    }

    const __bf16* Qrow = Qw + ((size_t)bh * SEQ + q0 + n32) * HD + 8 * hi;
    bf16x8 qf[4];
    #pragma unroll
    for (int d = 0; d < 4; ++d) qf[d] = load_bf16x8(Qrow + d * 16);

    bf16x8 qone;
    #pragma unroll
    for (int j = 0; j < 8; ++j) qone[j] = (__bf16)0.0f;
    if (hi == 0) qone[0] = (__bf16)1.0f;   // B[k=0][q] = 1

    const __bf16* kfb_ = Kf + (size_t)bh * SEQ * HD + (size_t)lane * 8;
    const __bf16* vfb_ = Vf + (size_t)bh * SEQ * HD + (size_t)lane * 8;

    f32x16 o0 = {0,0,0,0,0,0,0,0,0,0,0,0,0,0,0,0};
    f32x16 o1 = {0,0,0,0,0,0,0,0,0,0,0,0,0,0,0,0};
    f32x2 lsl2 = {0.f, 0.f};

    const int kstart = w * 512;
    const int blk0   = kstart >> 6;       // w*8

    // preload K halves 0 (cur) and 1 (nxt)
    bf16x8 kcur[4], knxt[4];
    {
        const size_t f0 = (size_t)blk0 * 4096;
        #pragma unroll
        for (int d = 0; d < 4; ++d) {
            kcur[d] = load_bf16x8(kfb_ + f0 + (size_t)(2 * d) * 512);
            knxt[d] = load_bf16x8(kfb_ + f0 + (size_t)(2 * d + 1) * 512);
        }
    }

    // S_cur for half 0
    f32x16 scur = {0,0,0,0,0,0,0,0,0,0,0,0,0,0,0,0};
    {
        bf16x8 mf;
        #pragma unroll
        for (int j = 0; j < 8; ++j) mf[j] = (__bf16)0.0f;
        mf[0] = mdd[kstart + n32];
        #pragma unroll
        for (int d = 0; d < 4; ++d)
            scur = __builtin_amdgcn_mfma_f32_32x32x16_bf16(kcur[d], qf[d], scur, 0, 0, 0);
        scur = __builtin_amdgcn_mfma_f32_32x32x16_bf16(mf, qone, scur, 0, 0, 0);
    }

    for (int hh = 0; hh < 16; ++hh) {
        const int h2 = (hh + 2) & 15;
        const int h1 = (hh + 1) & 15;
        const int p  = hh & 1;
        const int p2 = h2 & 1;
        const size_t foff_h  = (size_t)(blk0 + (hh >> 1)) * 4096;
        const size_t foff_h2 = (size_t)(blk0 + (h2 >> 1)) * 4096;

        // K prefetch for half hh+2 (consumed one full half-iter later)
        bf16x8 kpre[4];
        #pragma unroll
        for (int d = 0; d < 4; ++d)
            kpre[d] = load_bf16x8(kfb_ + foff_h2 + (size_t)(2 * d + p2) * 512);

        // V for this half
        bf16x8 v0[2], v1[2];
        #pragma unroll
        for (int e = 0; e < 2; ++e) {
            const int c = 2 * p + e;
            v0[e] = load_bf16x8(vfb_ + foff_h + (size_t)(2 * c) * 512);
            v1[e] = load_bf16x8(vfb_ + foff_h + (size_t)(2 * c + 1) * 512);
        }

        // S_next for half hh+1 — K loaded a half-iter ago; these 5 MFMAs
        // fill the matrix pipe while exp(S_cur) runs on the VALU below
        bf16x8 mf1;
        #pragma unroll
        for (int j = 0; j < 8; ++j) mf1[j] = (__bf16)0.0f;
        mf1[0] = mdd[kstart + h1 * 32 + n32];
        f32x16 snxt = {0,0,0,0,0,0,0,0,0,0,0,0,0,0,0,0};
        #pragma unroll
        for (int d = 0; d < 4; ++d)
            snxt = __builtin_amdgcn_mfma_f32_32x32x16_bf16(knxt[d], qf[d], snxt, 0, 0, 0);
        snxt = __builtin_amdgcn_mfma_f32_32x32x16_bf16(mf1, qone, snxt, 0, 0, 0);

        // exp/pack S_cur (VALU; overlaps snxt in the matrix pipe)
        bf16x8 P0, P1;
        {
            float pp[16];
            #pragma unroll
            for (int r = 0; r < 16; ++r) pp[r] = hw_exp2(scur[r]);
            u32x4 B0, B1;
            #pragma unroll
            for (int i = 0; i < 4; ++i) {
                B0[i] = cvtpk2(pp[2 * i],     pp[2 * i + 1]);
                B1[i] = cvtpk2(pp[8 + 2 * i], pp[8 + 2 * i + 1]);
            }
            #pragma unroll
            for (int i = 0; i < 8; ++i) {
                f32x2 t; t[0] = pp[2 * i]; t[1] = pp[2 * i + 1];
                lsl2 += t;
            }
            P0 = __builtin_bit_cast(bf16x8, B0);
            P1 = __builtin_bit_cast(bf16x8, B1);
        }

        // PV for this half
        o0 = __builtin_amdgcn_mfma_f32_32x32x16_bf16(v0[0], P0, o0, 0, 0, 0);
        o1 = __builtin_amdgcn_mfma_f32_32x32x16_bf16(v1[0], P0, o1, 0, 0, 0);
        o0 = __builtin_amdgcn_mfma_f32_32x32x16_bf16(v0[1], P1, o0, 0, 0, 0);
        o1 = __builtin_amdgcn_mfma_f32_32x32x16_bf16(v1[1], P1, o1, 0, 0, 0);

        // rotate pipeline state
        scur = snxt;
        #pragma unroll
        for (int d = 0; d < 4; ++d) knxt[d] = kpre[d];
    }

    float rs = lsl2[0] + lsl2[1];
    rs += __shfl_xor(rs, 32);

    __syncthreads();   // all waves past loop: mdd dead, safe to alias as et

    #pragma unroll
    for (int r = 0; r < 16; ++r) {
        const int dl = (r & 3) + 8 * (r >> 2) + 4 * hi;
        et[w][n32][dl]      = o0[r];
        et[w][n32][32 + dl] = o1[r];
    }
    if (lane < 32) lrow[w * 32 + n32] = rs;
    __syncthreads();

    const int q  = tid >> 3;
    const int d0 = (tid & 7) * 8;
    const float linv = 1.0f / (lrow[q] + lrow[32 + q] + lrow[64 + q] + lrow[96 + q]);
    f32x4 acc0 = {0,0,0,0}, acc1 = {0,0,0,0};
    #pragma unroll
    for (int ww = 0; ww < 4; ++ww) {
        acc0 += *(const f32x4*)&et[ww][q][d0];
        acc1 += *(const f32x4*)&et[ww][q][d0 + 4];
    }
    float* orow = out + ((size_t)(b_ * SEQ + q0 + q)) * NP + h * HD + d0;
    f32x4 r0, r1;
    #pragma unroll
    for (int i = 0; i < 4; ++i) { r0[i] = acc0[i] * linv; r1[i] = acc1[i] * linv; }
    *(f32x4*)(orow)     = r0;
    *(f32x4*)(orow + 4) = r1;
}

extern "C" void kernel_launch(void* const* d_in, const int* in_sizes, int n_in,
                              void* d_out, int out_size, void* d_ws, size_t ws_size,
                              hipStream_t stream) {
    const float* hidden = (const float*)d_in[0];
    const float* amask  = (const float*)d_in[1];
    const float* Wq     = (const float*)d_in[2];
    const float* bq     = (const float*)d_in[3];
    const float* Wk     = (const float*)d_in[4];
    const float* bk     = (const float*)d_in[5];
    const float* Wv     = (const float*)d_in[6];
    const float* bv     = (const float*)d_in[7];
    float* out = (float*)d_out;

    const size_t elems = (size_t)NB * NH * SEQ * HD; // 6,291,456
    __bf16* Qw = (__bf16*)d_ws;
    __bf16* Kf = Qw + elems;
    __bf16* Vf = Kf + elems;

    qkv_kernel<<<dim3(128, 2), 256, 0, stream>>>(
        hidden, Wq, Wk, Wv, bq, bk, bv, Qw, Kf, Vf);

    flash_attn_kernel<<<dim3(3072), 256, 0, stream>>>(
        Qw, Kf, Vf, amask, out);
}

// Round 17
// 166.601 us; speedup vs baseline: 1.0953x; 1.0953x over previous
//
#include <hip/hip_runtime.h>
#include <hip/hip_bf16.h>

#define NH 12
#define HD 64
#define NB 4
#define SEQ 2048
#define NP 768
#define LOG2E 1.44269504f
#define MASK_L2 14426.9504f   // 10000 * log2(e)

typedef __bf16 bf16x8 __attribute__((ext_vector_type(8)));
typedef __bf16 bf16x2 __attribute__((ext_vector_type(2)));
typedef float f32x2 __attribute__((ext_vector_type(2)));
typedef float f32x4 __attribute__((ext_vector_type(4)));
typedef float f32x16 __attribute__((ext_vector_type(16)));
typedef unsigned u32x4 __attribute__((ext_vector_type(4)));

static __device__ __forceinline__ bf16x8 load_bf16x8(const __bf16* p) {
    return *reinterpret_cast<const bf16x8*>(p);
}
static __device__ __forceinline__ float hw_exp2(float x) {
    return __builtin_amdgcn_exp2f(x);
}
// packed f32x2 -> bf16x2 (backend can select v_cvt_pk_bf16_f32 on gfx950)
static __device__ __forceinline__ unsigned cvtpk2(float lo, float hi) {
    f32x2 t; t[0] = lo; t[1] = hi;
    return __builtin_bit_cast(unsigned, __builtin_convertvector(t, bf16x2));
}

// ---------------------------------------------------------------------------
// Kernel 1 — best-measured qkv (rounds 12/13, non-flash gap 86.1 us):
// grid (128, 6); block = 64 t-rows; 6 (proj,head) tiles per block; W tile
// staged transposed+bf16 (+0.125*log2e for Q) in LDS; Vf written in
// SIGMA-PERMUTED key order sigma(8*hi+j) = (j&3)+8*(j>>2)+4*hi so flash
// needs no cross-lane exchange.
//   Q : row-major (bh, t, d)
//   Kf: per 64-key block [bh][kb64][frag 2*dstep+keyhalf][lane][8]
//   Vf: per 64-key block [bh][kb64][frag 2*keychunk+dhalf][lane][8], permuted
// ---------------------------------------------------------------------------
__global__ __launch_bounds__(256) void qkv_kernel(
    const float* __restrict__ hidden,
    const float* __restrict__ Wq, const float* __restrict__ Wk,
    const float* __restrict__ Wv,
    const float* __restrict__ bq, const float* __restrict__ bk,
    const float* __restrict__ bv,
    __bf16* __restrict__ Qw, __bf16* __restrict__ Kf, __bf16* __restrict__ Vf)
{
    __shared__ __bf16 wtileT[64][72];   // [c][k]
    __shared__ __bf16 ot[64][72];       // [t][c]

    const int tid  = threadIdx.x;
    const int lane = tid & 63;
    const int w    = tid >> 6;
    const int g    = lane >> 4;
    const int n    = lane & 15;
    const int n32  = lane & 31;
    const int hi   = lane >> 5;

    const int row0 = blockIdx.x * 64;
    const int gi   = blockIdx.y;          // 0..5
    const int b_   = row0 >> 11;
    const int t0   = row0 & (SEQ - 1);
    const int kb64 = t0 >> 6;

    const float* hrow = hidden + (size_t)(row0 + w * 16 + n) * HD + 8 * g;
    f32x4 h0 = *(const f32x4*)(hrow);
    f32x4 h1 = *(const f32x4*)(hrow + 4);
    f32x4 h2 = *(const f32x4*)(hrow + 32);
    f32x4 h3 = *(const f32x4*)(hrow + 36);
    bf16x8 a0, a1;
    #pragma unroll
    for (int j = 0; j < 4; ++j) {
        a0[j]     = (__bf16)h0[j];
        a0[j + 4] = (__bf16)h1[j];
        a1[j]     = (__bf16)h2[j];
        a1[j + 4] = (__bf16)h3[j];
    }

    const int dr   = tid >> 2;        // 0..63 (W row = k)
    const int coff = (tid & 3) * 16;  // 16 consecutive cols

    for (int tt = 0; tt < 6; ++tt) {
        const int tile_id = gi * 6 + tt;       // 0..35
        const int proj    = tile_id / 12;
        const int head    = tile_id % 12;
        const int bh      = b_ * NH + head;
        const float* W    = proj == 0 ? Wq : (proj == 1 ? Wk : Wv);
        const float* bias = proj == 0 ? bq : (proj == 1 ? bk : bv);
        const float qs    = (proj == 0) ? 0.125f * LOG2E : 1.0f;

        const float* wr = W + (size_t)dr * NP + head * 64 + coff;
        f32x4 x0 = *(const f32x4*)(wr);
        f32x4 x1 = *(const f32x4*)(wr + 4);
        f32x4 x2 = *(const f32x4*)(wr + 8);
        f32x4 x3 = *(const f32x4*)(wr + 12);
        #pragma unroll
        for (int i = 0; i < 4; ++i) {
            wtileT[coff + i     ][dr] = (__bf16)(x0[i] * qs);
            wtileT[coff + 4 + i ][dr] = (__bf16)(x1[i] * qs);
            wtileT[coff + 8 + i ][dr] = (__bf16)(x2[i] * qs);
            wtileT[coff + 12 + i][dr] = (__bf16)(x3[i] * qs);
        }
        __syncthreads();   // wtileT ready; also fences prev tile's ot reads

        #pragma unroll
        for (int dt = 0; dt < 4; ++dt) {
            const bf16x8 b0 = *(const bf16x8*)&wtileT[dt * 16 + n][8 * g];
            const bf16x8 b1 = *(const bf16x8*)&wtileT[dt * 16 + n][32 + 8 * g];
            f32x4 acc = {0.f, 0.f, 0.f, 0.f};
            acc = __builtin_amdgcn_mfma_f32_16x16x32_bf16(a0, b0, acc, 0, 0, 0);
            acc = __builtin_amdgcn_mfma_f32_16x16x32_bf16(a1, b1, acc, 0, 0, 0);
            const float bb = bias[head * 64 + dt * 16 + n] * qs;
            #pragma unroll
            for (int r = 0; r < 4; ++r)
                ot[w * 16 + 4 * g + r][dt * 16 + n] = (__bf16)(acc[r] + bb);
        }
        __syncthreads();   // ot complete; wtileT frag reads done

        if (proj == 0) {
            __bf16* dst = Qw + ((size_t)bh * SEQ + t0 + w * 16) * HD;
            const int tr = lane >> 2;
            const int d0 = (lane & 3) * 16;
            *(bf16x8*)(dst + (size_t)tr * HD + d0)     = *(const bf16x8*)&ot[w * 16 + tr][d0];
            *(bf16x8*)(dst + (size_t)tr * HD + d0 + 8) = *(const bf16x8*)&ot[w * 16 + tr][d0 + 8];
        } else if (proj == 1) {
            __bf16* base = Kf + (size_t)bh * SEQ * HD + (size_t)kb64 * 4096;
            #pragma unroll
            for (int sub = 0; sub < 2; ++sub) {
                const bf16x8 fr = *(const bf16x8*)&ot[sub * 32 + n32][w * 16 + 8 * hi];
                *(bf16x8*)(base + (size_t)(w * 2 + sub) * 512 + lane * 8) = fr;
            }
        } else {
            __bf16* base = Vf + (size_t)bh * SEQ * HD + (size_t)kb64 * 4096;
            #pragma unroll
            for (int dsub = 0; dsub < 2; ++dsub) {
                bf16x8 v;
                #pragma unroll
                for (int j = 0; j < 8; ++j)
                    v[j] = ot[w * 16 + ((j & 3) + 8 * (j >> 2) + 4 * hi)][dsub * 32 + n32];
                *(bf16x8*)(base + (size_t)(w * 2 + dsub) * 512 + lane * 8) = v;
            }
        }
    }
}

// ---------------------------------------------------------------------------
// Kernel 2 — best-measured flash (round 14's v13, 78.0 us): key-split waves,
// zero cross-lane ops in the loop, no prefetch (measured neutral), no SW
// pipeline (measured regression), mdd/et LDS union (35,328 B).
// ---------------------------------------------------------------------------
__global__ __launch_bounds__(256, 4) void flash_attn_kernel(
    const __bf16* __restrict__ Qw, const __bf16* __restrict__ Kf,
    const __bf16* __restrict__ Vf, const float* __restrict__ amask,
    float* __restrict__ out)
{
    __shared__ __align__(16) char smem[35328];
    __bf16* mdd = (__bf16*)smem;                      // loop phase (4 KB)
    float (*et)[32][68] = (float(*)[32][68])smem;     // epilogue (34,816 B)
    float* lrow = (float*)(smem + 34816);             // epilogue (512 B)

    const int tid  = threadIdx.x;
    const int lane = tid & 63;
    const int w    = tid >> 6;
    const int n32  = lane & 31;
    const int hi   = lane >> 5;

    const int bid    = blockIdx.x;        // 3072
    const int xcd    = bid & 7;
    const int slot   = bid >> 3;          // 0..383
    const int bh     = xcd * 6 + (slot >> 6);
    const int qchunk = slot & 63;
    const int b_     = bh / NH;
    const int h      = bh % NH;
    const int q0     = qchunk * 32;

    const float* mp = amask + (size_t)b_ * SEQ;
    #pragma unroll
    for (int i = 0; i < 8; ++i) {
        const int idx = w * 512 + i * 64 + lane;
        mdd[idx] = (__bf16)fmaf(mp[idx], MASK_L2, -MASK_L2);
    }

    const __bf16* Qrow = Qw + ((size_t)bh * SEQ + q0 + n32) * HD + 8 * hi;
    bf16x8 qf[4];
    #pragma unroll
    for (int d = 0; d < 4; ++d) qf[d] = load_bf16x8(Qrow + d * 16);

    bf16x8 qone;
    #pragma unroll
    for (int j = 0; j < 8; ++j) qone[j] = (__bf16)0.0f;
    if (hi == 0) qone[0] = (__bf16)1.0f;   // B[k=0][q] = 1

    const __bf16* kfb_ = Kf + (size_t)bh * SEQ * HD + (size_t)lane * 8;
    const __bf16* vfb_ = Vf + (size_t)bh * SEQ * HD + (size_t)lane * 8;

    f32x16 o0 = {0,0,0,0,0,0,0,0,0,0,0,0,0,0,0,0};
    f32x16 o1 = {0,0,0,0,0,0,0,0,0,0,0,0,0,0,0,0};
    f32x2 lsl2 = {0.f, 0.f};

    const int kstart = w * 512;
    for (int it = 0; it < 8; ++it) {
        const int kb = kstart + it * 64;
        const size_t foff = (size_t)(kb >> 6) * 4096;

        bf16x8 kfa[4], kfb[4], vf0[4], vf1[4];
        #pragma unroll
        for (int d = 0; d < 4; ++d) {
            kfa[d] = load_bf16x8(kfb_ + foff + (size_t)(2 * d) * 512);
            kfb[d] = load_bf16x8(kfb_ + foff + (size_t)(2 * d + 1) * 512);
        }
        #pragma unroll
        for (int c = 0; c < 4; ++c) {
            vf0[c] = load_bf16x8(vfb_ + foff + (size_t)(2 * c) * 512);
            vf1[c] = load_bf16x8(vfb_ + foff + (size_t)(2 * c + 1) * 512);
        }

        bf16x8 maa, mab;
        #pragma unroll
        for (int j = 0; j < 8; ++j) { maa[j] = (__bf16)0.0f; mab[j] = (__bf16)0.0f; }
        maa[0] = mdd[kb + n32];
        mab[0] = mdd[kb + 32 + n32];

        // ---- half 0 ----
        f32x16 sa = {0,0,0,0,0,0,0,0,0,0,0,0,0,0,0,0};
        #pragma unroll
        for (int d = 0; d < 4; ++d)
            sa = __builtin_amdgcn_mfma_f32_32x32x16_bf16(kfa[d], qf[d], sa, 0, 0, 0);
        sa = __builtin_amdgcn_mfma_f32_32x32x16_bf16(maa, qone, sa, 0, 0, 0);

        bf16x8 P0, P1;
        {
            float p[16];
            #pragma unroll
            for (int r = 0; r < 16; ++r) p[r] = hw_exp2(sa[r]);
            u32x4 B0, B1;
            #pragma unroll
            for (int i = 0; i < 4; ++i) {
                B0[i] = cvtpk2(p[2 * i],     p[2 * i + 1]);
                B1[i] = cvtpk2(p[8 + 2 * i], p[8 + 2 * i + 1]);
            }
            #pragma unroll
            for (int i = 0; i < 8; ++i) {
                f32x2 t; t[0] = p[2 * i]; t[1] = p[2 * i + 1];
                lsl2 += t;
            }
            P0 = __builtin_bit_cast(bf16x8, B0);
            P1 = __builtin_bit_cast(bf16x8, B1);
        }
        o0 = __builtin_amdgcn_mfma_f32_32x32x16_bf16(vf0[0], P0, o0, 0, 0, 0);
        o1 = __builtin_amdgcn_mfma_f32_32x32x16_bf16(vf1[0], P0, o1, 0, 0, 0);
        o0 = __builtin_amdgcn_mfma_f32_32x32x16_bf16(vf0[1], P1, o0, 0, 0, 0);
        o1 = __builtin_amdgcn_mfma_f32_32x32x16_bf16(vf1[1], P1, o1, 0, 0, 0);

        // ---- half 1 ----
        f32x16 sb = {0,0,0,0,0,0,0,0,0,0,0,0,0,0,0,0};
        #pragma unroll
        for (int d = 0; d < 4; ++d)
            sb = __builtin_amdgcn_mfma_f32_32x32x16_bf16(kfb[d], qf[d], sb, 0, 0, 0);
        sb = __builtin_amdgcn_mfma_f32_32x32x16_bf16(mab, qone, sb, 0, 0, 0);

        bf16x8 P2, P3;
        {
            float p[16];
            #pragma unroll
            for (int r = 0; r < 16; ++r) p[r] = hw_exp2(sb[r]);
            u32x4 B0, B1;
            #pragma unroll
            for (int i = 0; i < 4; ++i) {
                B0[i] = cvtpk2(p[2 * i],     p[2 * i + 1]);
                B1[i] = cvtpk2(p[8 + 2 * i], p[8 + 2 * i + 1]);
            }
            #pragma unroll
            for (int i = 0; i < 8; ++i) {
                f32x2 t; t[0] = p[2 * i]; t[1] = p[2 * i + 1];
                lsl2 += t;
            }
            P2 = __builtin_bit_cast(bf16x8, B0);
            P3 = __builtin_bit_cast(bf16x8, B1);
        }
        o0 = __builtin_amdgcn_mfma_f32_32x32x16_bf16(vf0[2], P2, o0, 0, 0, 0);
        o1 = __builtin_amdgcn_mfma_f32_32x32x16_bf16(vf1[2], P2, o1, 0, 0, 0);
        o0 = __builtin_amdgcn_mfma_f32_32x32x16_bf16(vf0[3], P3, o0, 0, 0, 0);
        o1 = __builtin_amdgcn_mfma_f32_32x32x16_bf16(vf1[3], P3, o1, 0, 0, 0);
    }

    float rs = lsl2[0] + lsl2[1];
    rs += __shfl_xor(rs, 32);

    __syncthreads();   // all waves past loop: mdd dead, safe to alias as et

    #pragma unroll
    for (int r = 0; r < 16; ++r) {
        const int dl = (r & 3) + 8 * (r >> 2) + 4 * hi;
        et[w][n32][dl]      = o0[r];
        et[w][n32][32 + dl] = o1[r];
    }
    if (lane < 32) lrow[w * 32 + n32] = rs;
    __syncthreads();

    const int q  = tid >> 3;
    const int d0 = (tid & 7) * 8;
    const float linv = 1.0f / (lrow[q] + lrow[32 + q] + lrow[64 + q] + lrow[96 + q]);
    f32x4 acc0 = {0,0,0,0}, acc1 = {0,0,0,0};
    #pragma unroll
    for (int ww = 0; ww < 4; ++ww) {
        acc0 += *(const f32x4*)&et[ww][q][d0];
        acc1 += *(const f32x4*)&et[ww][q][d0 + 4];
    }
    float* orow = out + ((size_t)(b_ * SEQ + q0 + q)) * NP + h * HD + d0;
    f32x4 r0, r1;
    #pragma unroll
    for (int i = 0; i < 4; ++i) { r0[i] = acc0[i] * linv; r1[i] = acc1[i] * linv; }
    *(f32x4*)(orow)     = r0;
    *(f32x4*)(orow + 4) = r1;
}

extern "C" void kernel_launch(void* const* d_in, const int* in_sizes, int n_in,
                              void* d_out, int out_size, void* d_ws, size_t ws_size,
                              hipStream_t stream) {
    const float* hidden = (const float*)d_in[0];
    const float* amask  = (const float*)d_in[1];
    const float* Wq     = (const float*)d_in[2];
    const float* bq     = (const float*)d_in[3];
    const float* Wk     = (const float*)d_in[4];
    const float* bk     = (const float*)d_in[5];
    const float* Wv     = (const float*)d_in[6];
    const float* bv     = (const float*)d_in[7];
    float* out = (float*)d_out;

    const size_t elems = (size_t)NB * NH * SEQ * HD; // 6,291,456
    __bf16* Qw = (__bf16*)d_ws;
    __bf16* Kf = Qw + elems;
    __bf16* Vf = Kf + elems;

    qkv_kernel<<<dim3(128, 6), 256, 0, stream>>>(
        hidden, Wq, Wk, Wv, bq, bk, bv, Qw, Kf, Vf);

    flash_attn_kernel<<<dim3(3072), 256, 0, stream>>>(
        Qw, Kf, Vf, amask, out);
}